// Round 11
// baseline (281.388 us; speedup 1.0000x reference)
//
#include <hip/hip_runtime.h>
#include <hip/hip_bf16.h>

#define B_ 64
#define S_ 1024
#define H_ 256
#define E_ 256

#define EG_ 16          // e-columns per k2 block (one MFMA N-tile)
#define LDSB_ST 264     // bf16 stride for B panel rows
#define CH_ 128         // rows per s-chunk (8 waves x 16)
#define NCH_ 8          // s-chunks per batch

typedef __attribute__((ext_vector_type(8))) __bf16 bf16x8;
typedef __attribute__((ext_vector_type(4))) __bf16 bf16x4;
typedef __attribute__((ext_vector_type(4))) float f32x4;

// ---- k0: blk<512 -> w[m]=exp(alpha.Wa+ba)*mask (16-lane coalesced, verified)
//          + Wb fp32->bf16 on blk<64;  blk>=512 -> beta fp32->bf16 streaming.
__global__ __launch_bounds__(256) void k0_prep(
        const float* __restrict__ alpha, const float* __restrict__ mask,
        const float* __restrict__ Wa,    const float* __restrict__ ba,
        const float* __restrict__ Wb,    const float* __restrict__ beta,
        __bf16* __restrict__ WbBf,       __bf16* __restrict__ betaBf,
        float* __restrict__ w) {
    const int tid = threadIdx.x, blk = blockIdx.x;
    if (blk >= 512) {                 // beta convert: 512 blocks x 256 thr x 32 f4
        const int base = (blk - 512) * 256 + tid;
        #pragma unroll 4
        for (int i = 0; i < 32; ++i) {
            const int idx = base + i * 131072;
            float4 v = ((const float4*)beta)[idx];
            bf16x4 bv;
            bv[0]=(__bf16)v.x; bv[1]=(__bf16)v.y; bv[2]=(__bf16)v.z; bv[3]=(__bf16)v.w;
            ((bf16x4*)betaBf)[idx] = bv;
        }
        return;
    }
    if (blk < 64) {
        int i = blk * 256 + tid;
        float4 v = ((const float4*)Wb)[i];
        bf16x4 bv;
        bv[0]=(__bf16)v.x; bv[1]=(__bf16)v.y; bv[2]=(__bf16)v.z; bv[3]=(__bf16)v.w;
        ((bf16x4*)WbBf)[i] = bv;
    }
    const int wv = tid >> 6, lane = tid & 63;
    const int rsub = lane >> 4, pcl = lane & 15;
    const float4* Wa4 = (const float4*)Wa;
    float4 wa0 = Wa4[pcl], wa1 = Wa4[pcl + 16],
           wa2 = Wa4[pcl + 32], wa3 = Wa4[pcl + 48];
    const float ba0 = ba[0];
    #pragma unroll 2
    for (int ps = 0; ps < 8; ++ps) {
        const int m = blk * 128 + ps * 16 + wv * 4 + rsub;
        const float4* ap = (const float4*)(alpha + (size_t)m * H_);
        float4 x0 = ap[pcl], x1 = ap[pcl + 16], x2 = ap[pcl + 32], x3 = ap[pcl + 48];
        float p = x0.x*wa0.x + x0.y*wa0.y + x0.z*wa0.z + x0.w*wa0.w
                + x1.x*wa1.x + x1.y*wa1.y + x1.z*wa1.z + x1.w*wa1.w
                + x2.x*wa2.x + x2.y*wa2.y + x2.z*wa2.z + x2.w*wa2.w
                + x3.x*wa3.x + x3.y*wa3.y + x3.z*wa3.z + x3.w*wa3.w;
        p += __shfl_xor(p, 1, 64);
        p += __shfl_xor(p, 2, 64);
        p += __shfl_xor(p, 4, 64);
        p += __shfl_xor(p, 8, 64);
        if (pcl == 0) w[m] = __expf(p + ba0) * mask[m];
    }
}

// ---- k2_bf: EG=16 (grid 1024 -> 4 blocks/CU), bf16 A, A+embed one-chunk-ahead
//  prefetch, light per-chunk barrier. Block=(batch b, 16 e-cols), 8 waves;
//  chunk c descending; wave wv owns rows [c*128 + wv*16, +16).
//  blk = eg*64 + b  =>  all 16 eg-blocks of batch b share blk%8 -> one XCD L2.
__global__ __launch_bounds__(512, 4) void k2_bf(
        const __bf16* __restrict__ betaBf, const float* __restrict__ embed,
        const __bf16* __restrict__ WbBf,   const float* __restrict__ bb,
        const float* __restrict__ w,       float* __restrict__ t) {
    __shared__ __bf16 ldsB[EG_ * LDSB_ST];   // 8.25 KB stationary B panel
    __shared__ float wsLds[S_];              // w[b, :]
    __shared__ float ivLds[S_];              // 1/(w-suffix + eps)
    __shared__ float red[2][8 * EG_];        // dbuf per-wave column totals
    __shared__ float run[2][EG_];            // dbuf cross-chunk carry
    __shared__ float wsum[4];

    const int tid = threadIdx.x;
    const int wv = tid >> 6, lane = tid & 63;
    const int l15 = lane & 15, q = lane >> 4;
    const int blk = blockIdx.x;
    const int b  = blk & 63;                 // batch  (blk%8 = b%8 -> XCD pin)
    const int eg = blk >> 6;                 // 0..15

    {   // stage B panel: 16 rows x 256 bf16 (512 thr x 16B)
        const int e = tid >> 5, ks = (tid & 31) * 8;
        *(bf16x8*)(ldsB + e * LDSB_ST + ks) =
            *(const bf16x8*)(WbBf + (size_t)(eg * EG_ + e) * H_ + ks);
    }
    if (tid < 256)
        *(float4*)(wsLds + tid * 4) = *(const float4*)(w + b * S_ + tid * 4);
    if (tid < 2 * EG_) run[tid >> 4][tid & 15] = 0.f;
    __syncthreads();

    {   // in-LDS suffix scan of w -> ivLds (verified R5/R10)
        float w0 = 0, w1 = 0, w2 = 0, w3 = 0, tot = 0, suf = 0;
        const int sl = tid & 63, sw = tid >> 6;
        if (tid < 256) {
            w0 = wsLds[tid * 4];     w1 = wsLds[tid * 4 + 1];
            w2 = wsLds[tid * 4 + 2]; w3 = wsLds[tid * 4 + 3];
            tot = w0 + w1 + w2 + w3;
            suf = tot;
            #pragma unroll
            for (int off = 1; off < 64; off <<= 1) {
                float o = __shfl_down(suf, off, 64);
                if (sl + off < 64) suf += o;
            }
            if (sl == 0) wsum[sw] = suf;
        }
        __syncthreads();
        if (tid < 256) {
            float waveOff = 0.f;
            for (int j = sw + 1; j < 4; ++j) waveOff += wsum[j];
            float after = (suf - tot) + waveOff;
            float s3 = w3 + after, s2 = w2 + s3, s1 = w1 + s2, s0 = w0 + s1;
            ivLds[tid * 4]     = 1.f / (s0 + 1e-10f);
            ivLds[tid * 4 + 1] = 1.f / (s1 + 1e-10f);
            ivLds[tid * 4 + 2] = 1.f / (s2 + 1e-10f);
            ivLds[tid * 4 + 3] = 1.f / (s3 + 1e-10f);
        }
        __syncthreads();
    }

    const float bb0 = bb[eg * EG_ + l15];
    const __bf16* Abase = betaBf + ((size_t)b * S_ + wv * 16 + l15) * H_ + q * 8;
    const size_t ebase = ((size_t)b * S_ + wv * 16 + q * 4) * E_ + eg * EG_;
    const float* E0 = embed + ebase + l15;
    float* T0 = t + ebase + l15;

    // prologue: prefetch chunk 7's A fragments + embed values
    bf16x8 nA[8];
    float eCur[4];
    {
        const size_t coff = (size_t)(NCH_ - 1) * CH_ * H_;
        #pragma unroll
        for (int kc = 0; kc < 8; ++kc)
            nA[kc] = *(const bf16x8*)(Abase + coff + (size_t)kc * 32);
        const size_t peoff = (size_t)(NCH_ - 1) * CH_ * E_;
        #pragma unroll
        for (int r = 0; r < 4; ++r)
            eCur[r] = E0[peoff + (size_t)r * E_];
    }

    #pragma unroll
    for (int si = 0; si < 8; ++si) {
        const int c = 7 - si;
        const int rb = si & 1;
        const size_t eoff = (size_t)c * CH_ * E_;

        bf16x8 curA[8];                 // SSA renames of landed prefetches
        #pragma unroll
        for (int kc = 0; kc < 8; ++kc) curA[kc] = nA[kc];
        float eUse[4];
        #pragma unroll
        for (int r = 0; r < 4; ++r) eUse[r] = eCur[r];

        // NEXT-chunk A + embed prefetch, issued BEFORE the MFMA chain
        if (c > 0) {
            const size_t poff = (size_t)(c - 1) * CH_ * H_;
            #pragma unroll
            for (int kc = 0; kc < 8; ++kc)
                nA[kc] = *(const bf16x8*)(Abase + poff + (size_t)kc * 32);
            const size_t peoff = (size_t)(c - 1) * CH_ * E_;
            #pragma unroll
            for (int r = 0; r < 4; ++r)
                eCur[r] = E0[peoff + (size_t)r * E_];
        }

        f32x4 acc0 = {0.f, 0.f, 0.f, 0.f};
        #pragma unroll
        for (int kc = 0; kc < 8; ++kc) {
            bf16x8 bf0 = *(const bf16x8*)(ldsB + l15 * LDSB_ST + kc * 32 + q * 8);
            acc0 = __builtin_amdgcn_mfma_f32_16x16x32_bf16(curA[kc], bf0, acc0, 0, 0, 0);
        }

        // epilogue: tanh * w * embed; 16-row in-tile suffix
        float wmr[4], iv[4];
        #pragma unroll
        for (int r = 0; r < 4; ++r) {
            wmr[r] = wsLds[c * CH_ + wv * 16 + q * 4 + r];
            iv[r]  = ivLds[c * CH_ + wv * 16 + q * 4 + r];
        }
        float sv0[4];
        {
            float tv[4];
            #pragma unroll
            for (int r = 0; r < 4; ++r) {
                float x = acc0[r] + bb0;
                x = fminf(fmaxf(x, -15.f), 15.f);
                float ex = __expf(2.f * x);
                tv[r] = wmr[r] * ((ex - 1.f) / (ex + 1.f)) * eUse[r];
            }
            float s3 = tv[3], s2 = tv[2] + s3, s1 = tv[1] + s2, s0 = tv[0] + s1;
            float g = s0;
            float g1 = __shfl_down(g, 16, 64);
            float g2 = __shfl_down(g, 32, 64);
            float g3 = __shfl_down(g, 48, 64);
            float addG = (q < 3 ? g1 : 0.f) + (q < 2 ? g2 : 0.f) + (q < 1 ? g3 : 0.f);
            if (q == 0) red[rb][wv * EG_ + l15] = g + addG;
            sv0[0] = s0 + addG; sv0[1] = s1 + addG;
            sv0[2] = s2 + addG; sv0[3] = s3 + addG;
        }

        // LIGHT barrier: drain LDS only; A/embed prefetch + t stores keep flying
        asm volatile("s_waitcnt lgkmcnt(0)" ::: "memory");
        __builtin_amdgcn_s_barrier();
        __builtin_amdgcn_sched_barrier(0);

        float nr0;
        {
            const float rn = run[rb][l15];
            float later = rn, tot = 0.f;
            #pragma unroll
            for (int w2 = 0; w2 < 8; ++w2) {
                float v = red[rb][w2 * EG_ + l15];
                tot += v;
                if (w2 > wv) later += v;
            }
            nr0 = rn + tot;
            #pragma unroll
            for (int r = 0; r < 4; ++r)
                T0[eoff + (size_t)r * E_] = (sv0[r] + later) * iv[r];
        }
        if (wv == 0 && q == 0)          // next chunk's carry (other buffer)
            run[rb ^ 1][l15] = nr0;
        // next chunk's barrier orders this write before its readers
    }
}

extern "C" void kernel_launch(void* const* d_in, const int* in_sizes, int n_in,
                              void* d_out, int out_size, void* d_ws, size_t ws_size,
                              hipStream_t stream) {
    const float* alpha = (const float*)d_in[0];
    const float* beta  = (const float*)d_in[1];
    const float* embed = (const float*)d_in[2];
    const float* mask  = (const float*)d_in[3];
    const float* Wb    = (const float*)d_in[4];
    const float* bbp   = (const float*)d_in[5];
    const float* Wa    = (const float*)d_in[6];
    const float* bap   = (const float*)d_in[7];

    char* ws = (char*)d_ws;
    float*  w      = (float*)ws;                       // 256 KB
    __bf16* WbBf   = (__bf16*)(ws + (256 << 10));      // 128 KB
    __bf16* betaBf = (__bf16*)(ws + (512 << 10));      // 32 MB  (proven to fit, R10)

    k0_prep<<<1024, 256, 0, stream>>>(alpha, mask, Wa, bap, Wb, beta,
                                      WbBf, betaBf, w);
    k2_bf<<<B_ * (E_ / EG_), 512, 0, stream>>>(betaBf, embed, WbBf, bbp, w,
                                               (float*)d_out);
}

// Round 12
// 260.137 us; speedup vs baseline: 1.0817x; 1.0817x over previous
//
#include <hip/hip_runtime.h>
#include <hip/hip_bf16.h>

#define B_ 64
#define S_ 1024
#define H_ 256
#define E_ 256

#define EG_ 32          // e-columns per k2 block (PROVEN best, R10)
#define LDSB_ST 264     // bf16 stride for B panel rows
#define CH_ 128         // rows per s-chunk (8 waves x 16)
#define NCH_ 8          // s-chunks per batch

typedef __attribute__((ext_vector_type(8))) __bf16 bf16x8;
typedef __attribute__((ext_vector_type(4))) __bf16 bf16x4;
typedef __attribute__((ext_vector_type(4))) float f32x4;

// ---- k0: blk<512 -> w[m]=exp(alpha.Wa+ba)*mask (16-lane coalesced, verified)
//          + Wb fp32->bf16 on blk<64;  blk>=512 -> beta fp32->bf16 streaming.
__global__ __launch_bounds__(256) void k0_prep(
        const float* __restrict__ alpha, const float* __restrict__ mask,
        const float* __restrict__ Wa,    const float* __restrict__ ba,
        const float* __restrict__ Wb,    const float* __restrict__ beta,
        __bf16* __restrict__ WbBf,       __bf16* __restrict__ betaBf,
        float* __restrict__ w) {
    const int tid = threadIdx.x, blk = blockIdx.x;
    if (blk >= 512) {                 // beta convert: 512 blocks x 256 thr x 32 f4
        const int base = (blk - 512) * 256 + tid;
        #pragma unroll 4
        for (int i = 0; i < 32; ++i) {
            const int idx = base + i * 131072;
            float4 v = ((const float4*)beta)[idx];
            bf16x4 bv;
            bv[0]=(__bf16)v.x; bv[1]=(__bf16)v.y; bv[2]=(__bf16)v.z; bv[3]=(__bf16)v.w;
            ((bf16x4*)betaBf)[idx] = bv;
        }
        return;
    }
    if (blk < 64) {
        int i = blk * 256 + tid;
        float4 v = ((const float4*)Wb)[i];
        bf16x4 bv;
        bv[0]=(__bf16)v.x; bv[1]=(__bf16)v.y; bv[2]=(__bf16)v.z; bv[3]=(__bf16)v.w;
        ((bf16x4*)WbBf)[i] = bv;
    }
    const int wv = tid >> 6, lane = tid & 63;
    const int rsub = lane >> 4, pcl = lane & 15;
    const float4* Wa4 = (const float4*)Wa;
    float4 wa0 = Wa4[pcl], wa1 = Wa4[pcl + 16],
           wa2 = Wa4[pcl + 32], wa3 = Wa4[pcl + 48];
    const float ba0 = ba[0];
    #pragma unroll 2
    for (int ps = 0; ps < 8; ++ps) {
        const int m = blk * 128 + ps * 16 + wv * 4 + rsub;
        const float4* ap = (const float4*)(alpha + (size_t)m * H_);
        float4 x0 = ap[pcl], x1 = ap[pcl + 16], x2 = ap[pcl + 32], x3 = ap[pcl + 48];
        float p = x0.x*wa0.x + x0.y*wa0.y + x0.z*wa0.z + x0.w*wa0.w
                + x1.x*wa1.x + x1.y*wa1.y + x1.z*wa1.z + x1.w*wa1.w
                + x2.x*wa2.x + x2.y*wa2.y + x2.z*wa2.z + x2.w*wa2.w
                + x3.x*wa3.x + x3.y*wa3.y + x3.z*wa3.z + x3.w*wa3.w;
        p += __shfl_xor(p, 1, 64);
        p += __shfl_xor(p, 2, 64);
        p += __shfl_xor(p, 4, 64);
        p += __shfl_xor(p, 8, 64);
        if (pcl == 0) w[m] = __expf(p + ba0) * mask[m];
    }
}

// ---- k2_bf: R10 verbatim (EG=32, bf16 A, 1-deep A prefetch, light barrier)
//      + ONE change: embed values prefetched one chunk ahead (eCur/eUse SSA).
__global__ __launch_bounds__(512, 4) void k2_bf(
        const __bf16* __restrict__ betaBf, const float* __restrict__ embed,
        const __bf16* __restrict__ WbBf,   const float* __restrict__ bb,
        const float* __restrict__ w,       float* __restrict__ t) {
    __shared__ __bf16 ldsB[EG_ * LDSB_ST];   // 16.5 KB stationary B panel
    __shared__ float wsLds[S_];              // w[b, :]
    __shared__ float ivLds[S_];              // 1/(w-suffix + eps)
    __shared__ float red[2][8 * EG_];        // dbuf per-wave column totals
    __shared__ float run[2][EG_];            // dbuf cross-chunk carry
    __shared__ float wsum[4];

    const int tid = threadIdx.x;
    const int wv = tid >> 6, lane = tid & 63;
    const int l15 = lane & 15, q = lane >> 4;
    const int blk = blockIdx.x;
    // XCD co-location: 8 e-group blocks of a batch share blk%8 -> one XCD L2
    const int b  = (blk & 7) * 8 + (blk >> 6);
    const int eg = (blk >> 3) & 7;

    {   // stage B panel + w
        const int e = tid >> 4, kq = (tid & 15) * 16;
        const __bf16* src = WbBf + (size_t)(eg * EG_ + e) * H_ + kq;
        *(bf16x8*)(ldsB + e * LDSB_ST + kq)     = *(const bf16x8*)(src);
        *(bf16x8*)(ldsB + e * LDSB_ST + kq + 8) = *(const bf16x8*)(src + 8);
    }
    if (tid < 256)
        *(float4*)(wsLds + tid * 4) = *(const float4*)(w + b * S_ + tid * 4);
    if (tid < 64) run[tid >> 5][tid & 31] = 0.f;
    __syncthreads();

    {   // in-LDS suffix scan of w -> ivLds (verified R5/R10)
        float w0 = 0, w1 = 0, w2 = 0, w3 = 0, tot = 0, suf = 0;
        const int sl = tid & 63, sw = tid >> 6;
        if (tid < 256) {
            w0 = wsLds[tid * 4];     w1 = wsLds[tid * 4 + 1];
            w2 = wsLds[tid * 4 + 2]; w3 = wsLds[tid * 4 + 3];
            tot = w0 + w1 + w2 + w3;
            suf = tot;
            #pragma unroll
            for (int off = 1; off < 64; off <<= 1) {
                float o = __shfl_down(suf, off, 64);
                if (sl + off < 64) suf += o;
            }
            if (sl == 0) wsum[sw] = suf;
        }
        __syncthreads();
        if (tid < 256) {
            float waveOff = 0.f;
            for (int j = sw + 1; j < 4; ++j) waveOff += wsum[j];
            float after = (suf - tot) + waveOff;
            float s3 = w3 + after, s2 = w2 + s3, s1 = w1 + s2, s0 = w0 + s1;
            ivLds[tid * 4]     = 1.f / (s0 + 1e-10f);
            ivLds[tid * 4 + 1] = 1.f / (s1 + 1e-10f);
            ivLds[tid * 4 + 2] = 1.f / (s2 + 1e-10f);
            ivLds[tid * 4 + 3] = 1.f / (s3 + 1e-10f);
        }
        __syncthreads();
    }

    const float bb0 = bb[eg * EG_ + l15];
    const float bb1 = bb[eg * EG_ + 16 + l15];
    const __bf16* Abase = betaBf + ((size_t)b * S_ + wv * 16 + l15) * H_ + q * 8;
    const size_t ebase = ((size_t)b * S_ + wv * 16 + q * 4) * E_ + eg * EG_;
    const float* E0 = embed + ebase + l15;
    const float* E1 = E0 + 16;
    float* T0 = t + ebase + l15;
    float* T1 = T0 + 16;

    // prologue: prefetch chunk 7's A fragments AND embed values
    bf16x8 nA[8];
    float eCur0[4], eCur1[4];
    {
        const size_t coff = (size_t)(NCH_ - 1) * CH_ * H_;
        #pragma unroll
        for (int kc = 0; kc < 8; ++kc)
            nA[kc] = *(const bf16x8*)(Abase + coff + (size_t)kc * 32);
        const size_t peoff = (size_t)(NCH_ - 1) * CH_ * E_;
        #pragma unroll
        for (int r = 0; r < 4; ++r) {
            eCur0[r] = E0[peoff + (size_t)r * E_];
            eCur1[r] = E1[peoff + (size_t)r * E_];
        }
    }

    #pragma unroll
    for (int si = 0; si < 8; ++si) {
        const int c = 7 - si;
        const int rb = si & 1;
        const size_t eoff = (size_t)c * CH_ * E_;

        bf16x8 curA[8];                 // SSA renames of landed prefetches
        #pragma unroll
        for (int kc = 0; kc < 8; ++kc) curA[kc] = nA[kc];
        float eUse0[4], eUse1[4];
        #pragma unroll
        for (int r = 0; r < 4; ++r) { eUse0[r] = eCur0[r]; eUse1[r] = eCur1[r]; }

        // NEXT-chunk A + embed prefetch, issued BEFORE the MFMA chain
        if (c > 0) {
            const size_t poff = (size_t)(c - 1) * CH_ * H_;
            #pragma unroll
            for (int kc = 0; kc < 8; ++kc)
                nA[kc] = *(const bf16x8*)(Abase + poff + (size_t)kc * 32);
            const size_t peoff = (size_t)(c - 1) * CH_ * E_;
            #pragma unroll
            for (int r = 0; r < 4; ++r) {
                eCur0[r] = E0[peoff + (size_t)r * E_];
                eCur1[r] = E1[peoff + (size_t)r * E_];
            }
        }

        f32x4 acc0 = {0.f, 0.f, 0.f, 0.f}, acc1 = {0.f, 0.f, 0.f, 0.f};
        #pragma unroll
        for (int kc = 0; kc < 8; ++kc) {
            bf16x8 bf0 = *(const bf16x8*)(ldsB + l15 * LDSB_ST + kc * 32 + q * 8);
            bf16x8 bf1 = *(const bf16x8*)(ldsB + (16 + l15) * LDSB_ST + kc * 32 + q * 8);
            acc0 = __builtin_amdgcn_mfma_f32_16x16x32_bf16(curA[kc], bf0, acc0, 0, 0, 0);
            acc1 = __builtin_amdgcn_mfma_f32_16x16x32_bf16(curA[kc], bf1, acc1, 0, 0, 0);
        }

        // epilogue: tanh * w * embed; 16-row in-tile suffix
        float wmr[4], iv[4];
        #pragma unroll
        for (int r = 0; r < 4; ++r) {
            wmr[r] = wsLds[c * CH_ + wv * 16 + q * 4 + r];
            iv[r]  = ivLds[c * CH_ + wv * 16 + q * 4 + r];
        }
        float sv0[4], sv1[4];
        {
            float tv[4];
            #pragma unroll
            for (int r = 0; r < 4; ++r) {
                float x = acc0[r] + bb0;
                x = fminf(fmaxf(x, -15.f), 15.f);
                float ex = __expf(2.f * x);
                tv[r] = wmr[r] * ((ex - 1.f) / (ex + 1.f)) * eUse0[r];
            }
            float s3 = tv[3], s2 = tv[2] + s3, s1 = tv[1] + s2, s0 = tv[0] + s1;
            float g = s0;
            float g1 = __shfl_down(g, 16, 64);
            float g2 = __shfl_down(g, 32, 64);
            float g3 = __shfl_down(g, 48, 64);
            float addG = (q < 3 ? g1 : 0.f) + (q < 2 ? g2 : 0.f) + (q < 1 ? g3 : 0.f);
            if (q == 0) red[rb][wv * EG_ + l15] = g + addG;
            sv0[0] = s0 + addG; sv0[1] = s1 + addG;
            sv0[2] = s2 + addG; sv0[3] = s3 + addG;
        }
        {
            float tv[4];
            #pragma unroll
            for (int r = 0; r < 4; ++r) {
                float x = acc1[r] + bb1;
                x = fminf(fmaxf(x, -15.f), 15.f);
                float ex = __expf(2.f * x);
                tv[r] = wmr[r] * ((ex - 1.f) / (ex + 1.f)) * eUse1[r];
            }
            float s3 = tv[3], s2 = tv[2] + s3, s1 = tv[1] + s2, s0 = tv[0] + s1;
            float g = s0;
            float g1 = __shfl_down(g, 16, 64);
            float g2 = __shfl_down(g, 32, 64);
            float g3 = __shfl_down(g, 48, 64);
            float addG = (q < 3 ? g1 : 0.f) + (q < 2 ? g2 : 0.f) + (q < 1 ? g3 : 0.f);
            if (q == 0) red[rb][wv * EG_ + 16 + l15] = g + addG;
            sv1[0] = s0 + addG; sv1[1] = s1 + addG;
            sv1[2] = s2 + addG; sv1[3] = s3 + addG;
        }

        // LIGHT barrier: drain LDS only; A/embed prefetch + t stores keep flying
        asm volatile("s_waitcnt lgkmcnt(0)" ::: "memory");
        __builtin_amdgcn_s_barrier();
        __builtin_amdgcn_sched_barrier(0);

        float nr0, nr1;
        {
            const float rn = run[rb][l15];
            float later = rn, tot = 0.f;
            #pragma unroll
            for (int w2 = 0; w2 < 8; ++w2) {
                float v = red[rb][w2 * EG_ + l15];
                tot += v;
                if (w2 > wv) later += v;
            }
            nr0 = rn + tot;
            #pragma unroll
            for (int r = 0; r < 4; ++r)
                T0[eoff + (size_t)r * E_] = (sv0[r] + later) * iv[r];
        }
        {
            const float rn = run[rb][16 + l15];
            float later = rn, tot = 0.f;
            #pragma unroll
            for (int w2 = 0; w2 < 8; ++w2) {
                float v = red[rb][w2 * EG_ + 16 + l15];
                tot += v;
                if (w2 > wv) later += v;
            }
            nr1 = rn + tot;
            #pragma unroll
            for (int r = 0; r < 4; ++r)
                T1[eoff + (size_t)r * E_] = (sv1[r] + later) * iv[r];
        }
        if (wv == 0 && q == 0) {        // next chunk's carry (other buffer)
            run[rb ^ 1][l15] = nr0;
            run[rb ^ 1][16 + l15] = nr1;
        }
        // next chunk's barrier orders this write before its readers
    }
}

extern "C" void kernel_launch(void* const* d_in, const int* in_sizes, int n_in,
                              void* d_out, int out_size, void* d_ws, size_t ws_size,
                              hipStream_t stream) {
    const float* alpha = (const float*)d_in[0];
    const float* beta  = (const float*)d_in[1];
    const float* embed = (const float*)d_in[2];
    const float* mask  = (const float*)d_in[3];
    const float* Wb    = (const float*)d_in[4];
    const float* bbp   = (const float*)d_in[5];
    const float* Wa    = (const float*)d_in[6];
    const float* bap   = (const float*)d_in[7];

    char* ws = (char*)d_ws;
    float*  w      = (float*)ws;                       // 256 KB
    __bf16* WbBf   = (__bf16*)(ws + (256 << 10));      // 128 KB
    __bf16* betaBf = (__bf16*)(ws + (512 << 10));      // 32 MB  (proven to fit, R10)

    k0_prep<<<1024, 256, 0, stream>>>(alpha, mask, Wa, bap, Wb, beta,
                                      WbBf, betaBf, w);
    k2_bf<<<B_ * (E_ / EG_), 512, 0, stream>>>(betaBf, embed, WbBf, bbp, w,
                                               (float*)d_out);
}